// Round 1
// baseline (2077.017 us; speedup 1.0000x reference)
//
#include <hip/hip_runtime.h>
#include <hip/hip_bf16.h>
#include <math.h>

#define BATCH 65536
#define DIM 256
#define KC 1024
#define COMMIT 0.25f
#define DECAY 0.99f
#define EPSV 1e-5f

// Output layout (floats, concatenated in reference return order)
#define O_ZQ   0                       // 65536*256
#define O_LOSS 16777216                // 1
#define O_PERP 16777217                // 1
#define O_IDX  16777218                // 65536 (indices written as float values)
#define O_EMB  16842754                // 1024*256 new_embedding
#define O_NCS  17104898                // 1024 new_ema_cluster_size
#define O_NEW  17105922                // 1024*256 new_ema_w

// ---------------- zero accumulators (ws is re-poisoned 0xAA every launch) ---
__global__ __launch_bounds__(256) void zero_kernel(float* __restrict__ dw,
                                                   float* __restrict__ cs,
                                                   float* __restrict__ loss) {
    int i = blockIdx.x * 256 + threadIdx.x;
    if (i < KC * DIM) dw[i] = 0.0f;
    if (i < KC) cs[i] = 0.0f;
    if (i == 0) loss[0] = 0.0f;
}

// ---------------- e_sq[k] = sum_d emb[k][d]^2 ------------------------------
__global__ __launch_bounds__(64) void esq_kernel(const float* __restrict__ emb,
                                                 float* __restrict__ e_sq) {
    int k = blockIdx.x;
    int lane = threadIdx.x;
    const float4* ep = (const float4*)(emb + (size_t)k * DIM);
    float4 e = ep[lane];                 // 64 lanes x float4 = 256 elems
    float s = e.x * e.x + e.y * e.y + e.z * e.z + e.w * e.w;
    for (int off = 32; off; off >>= 1) s += __shfl_down(s, off, 64);
    if (lane == 0) e_sq[k] = s;
}

// ---------------- argmin_k (e_sq[k] - 2 * z.e_k) per row --------------------
// 64 rows per block (z tile in LDS), 256 threads, 4 rows x 4 ks micro-tile.
__global__ __launch_bounds__(256) void argmin_kernel(
        const float* __restrict__ z_e, const float* __restrict__ emb,
        const float* __restrict__ e_sq, int* __restrict__ idx_out,
        float* __restrict__ idx_f_out) {
    __shared__ float zs[64 * DIM];          // 64 KB
    __shared__ float rb[64][16];
    __shared__ int   rk[64][16];

    int tid = threadIdx.x;
    int row0 = blockIdx.x * 64;

    // stage z tile (coalesced float4)
    const float4* zg = (const float4*)(z_e + (size_t)row0 * DIM);
    float4* zs4 = (float4*)zs;
    #pragma unroll
    for (int i = 0; i < 16; ++i) zs4[tid + i * 256] = zg[tid + i * 256];
    __syncthreads();

    int tx = tid & 15;   // k group
    int ty = tid >> 4;   // row group: rows ty*4 .. ty*4+3

    float best[4] = {1e30f, 1e30f, 1e30f, 1e30f};
    int bestk[4] = {0, 0, 0, 0};

    const float4* z0 = (const float4*)(zs + (ty * 4 + 0) * DIM);
    const float4* z1 = (const float4*)(zs + (ty * 4 + 1) * DIM);
    const float4* z2 = (const float4*)(zs + (ty * 4 + 2) * DIM);
    const float4* z3 = (const float4*)(zs + (ty * 4 + 3) * DIM);

    for (int kt = 0; kt < 16; ++kt) {
        int kbase = kt * 64 + tx * 4;
        const float4* e0 = (const float4*)(emb + (size_t)(kbase + 0) * DIM);
        const float4* e1 = (const float4*)(emb + (size_t)(kbase + 1) * DIM);
        const float4* e2 = (const float4*)(emb + (size_t)(kbase + 2) * DIM);
        const float4* e3 = (const float4*)(emb + (size_t)(kbase + 3) * DIM);

        float acc[4][4];
        #pragma unroll
        for (int r = 0; r < 4; ++r)
            #pragma unroll
            for (int c = 0; c < 4; ++c) acc[r][c] = 0.0f;

        #pragma unroll 8
        for (int d = 0; d < DIM / 4; ++d) {
            float4 ea = e0[d], eb = e1[d], ec = e2[d], ed = e3[d];
            float4 za = z0[d], zb = z1[d], zc = z2[d], zd = z3[d];
            acc[0][0] += za.x*ea.x + za.y*ea.y + za.z*ea.z + za.w*ea.w;
            acc[0][1] += za.x*eb.x + za.y*eb.y + za.z*eb.z + za.w*eb.w;
            acc[0][2] += za.x*ec.x + za.y*ec.y + za.z*ec.z + za.w*ec.w;
            acc[0][3] += za.x*ed.x + za.y*ed.y + za.z*ed.z + za.w*ed.w;
            acc[1][0] += zb.x*ea.x + zb.y*ea.y + zb.z*ea.z + zb.w*ea.w;
            acc[1][1] += zb.x*eb.x + zb.y*eb.y + zb.z*eb.z + zb.w*eb.w;
            acc[1][2] += zb.x*ec.x + zb.y*ec.y + zb.z*ec.z + zb.w*ec.w;
            acc[1][3] += zb.x*ed.x + zb.y*ed.y + zb.z*ed.z + zb.w*ed.w;
            acc[2][0] += zc.x*ea.x + zc.y*ea.y + zc.z*ea.z + zc.w*ea.w;
            acc[2][1] += zc.x*eb.x + zc.y*eb.y + zc.z*eb.z + zc.w*eb.w;
            acc[2][2] += zc.x*ec.x + zc.y*ec.y + zc.z*ec.z + zc.w*ec.w;
            acc[2][3] += zc.x*ed.x + zc.y*ed.y + zc.z*ed.z + zc.w*ed.w;
            acc[3][0] += zd.x*ea.x + zd.y*ea.y + zd.z*ea.z + zd.w*ea.w;
            acc[3][1] += zd.x*eb.x + zd.y*eb.y + zd.z*eb.z + zd.w*eb.w;
            acc[3][2] += zd.x*ec.x + zd.y*ec.y + zd.z*ec.z + zd.w*ec.w;
            acc[3][3] += zd.x*ed.x + zd.y*ed.y + zd.z*ed.z + zd.w*ed.w;
        }

        #pragma unroll
        for (int r = 0; r < 4; ++r) {
            #pragma unroll
            for (int c = 0; c < 4; ++c) {
                float s = e_sq[kbase + c] - 2.0f * acc[r][c];
                if (s < best[r]) { best[r] = s; bestk[r] = kbase + c; }
            }
        }
    }

    #pragma unroll
    for (int r = 0; r < 4; ++r) {
        rb[ty * 4 + r][tx] = best[r];
        rk[ty * 4 + r][tx] = bestk[r];
    }
    __syncthreads();

    if (tid < 64) {
        float bv = rb[tid][0];
        int bk = rk[tid][0];
        #pragma unroll
        for (int j = 1; j < 16; ++j) {
            float v = rb[tid][j];
            int kk = rk[tid][j];
            if (v < bv || (v == bv && kk < bk)) { bv = v; bk = kk; }
        }
        idx_out[row0 + tid] = bk;
        idx_f_out[row0 + tid] = (float)bk;
    }
}

// ---------------- gather z_q, loss, cluster_size, dw ------------------------
__global__ __launch_bounds__(256) void scatter_kernel(
        const float* __restrict__ z_e, const float* __restrict__ emb,
        const int* __restrict__ idx, float* __restrict__ zq_out,
        float* __restrict__ dw, float* __restrict__ cs,
        float* __restrict__ loss) {
    int tid = threadIdx.x;   // = d
    int row0 = blockIdx.x * 64;
    float lsum = 0.0f;
    for (int r = 0; r < 64; ++r) {
        int row = row0 + r;
        int k = idx[row];
        float z = z_e[(size_t)row * DIM + tid];
        float q = emb[(size_t)k * DIM + tid];
        zq_out[(size_t)row * DIM + tid] = z + (q - z);   // mimic z_e + (z_q - z_e)
        float dlt = q - z;
        lsum += dlt * dlt;
        atomicAdd(&dw[(size_t)k * DIM + tid], z);
        if (tid == 0) atomicAdd(&cs[k], 1.0f);
    }
    __shared__ float red[256];
    red[tid] = lsum;
    __syncthreads();
    for (int s = 128; s; s >>= 1) {
        if (tid < s) red[tid] += red[tid + s];
        __syncthreads();
    }
    if (tid == 0) atomicAdd(loss, red[0]);
}

// ---------------- per-cluster EMA, n, perplexity, loss ----------------------
__global__ __launch_bounds__(1024) void finalize_cluster(
        const float* __restrict__ ema_cs, const float* __restrict__ cs,
        const float* __restrict__ loss, float* __restrict__ out,
        float* __restrict__ n_ws) {
    __shared__ float s1[1024];
    __shared__ float s2[1024];
    int t = threadIdx.x;
    float c = cs[t];
    float ncs = DECAY * ema_cs[t] + (1.0f - DECAY) * c;
    out[O_NCS + t] = ncs;
    float p = c / (float)BATCH;
    s1[t] = ncs;
    s2[t] = p * logf(p + 1e-10f);
    __syncthreads();
    for (int s = 512; s; s >>= 1) {
        if (t < s) { s1[t] += s1[t + s]; s2[t] += s2[t + s]; }
        __syncthreads();
    }
    if (t == 0) {
        n_ws[0] = s1[0];
        out[O_PERP] = expf(-s2[0]);
        out[O_LOSS] = COMMIT * loss[0] / (float)((size_t)BATCH * DIM);
    }
}

// ---------------- new_ema_w and new_embedding -------------------------------
__global__ __launch_bounds__(256) void finalize_emb(
        const float* __restrict__ ema_w, const float* __restrict__ dw,
        const float* __restrict__ ncs_arr, const float* __restrict__ n_ws,
        float* __restrict__ out_emb, float* __restrict__ out_emaw) {
    int k = blockIdx.x;
    int d = threadIdx.x;
    size_t i = (size_t)k * DIM + d;
    float w = DECAY * ema_w[i] + (1.0f - DECAY) * dw[i];
    out_emaw[i] = w;
    float n = n_ws[0];
    float ncs = ncs_arr[k];
    float smoothed = (ncs + EPSV) / (n + (float)KC * EPSV) * n;
    out_emb[i] = w / smoothed;
}

extern "C" void kernel_launch(void* const* d_in, const int* in_sizes, int n_in,
                              void* d_out, int out_size, void* d_ws, size_t ws_size,
                              hipStream_t stream) {
    const float* z_e    = (const float*)d_in[0];
    const float* emb    = (const float*)d_in[1];
    const float* ema_cs = (const float*)d_in[2];
    const float* ema_w  = (const float*)d_in[3];
    float* out = (float*)d_out;
    float* ws = (float*)d_ws;

    // workspace layout
    float* e_sq = ws;                          // 1024
    int*   idx  = (int*)(ws + 1024);           // 65536
    float* cs   = ws + 1024 + 65536;           // 1024
    float* loss = cs + 1024;                   // 1
    float* n_ws = loss + 1;                    // 1
    float* dw   = n_ws + 1;                    // 1024*256

    zero_kernel<<<dim3(1024), dim3(256), 0, stream>>>(dw, cs, loss);
    esq_kernel<<<dim3(KC), dim3(64), 0, stream>>>(emb, e_sq);
    argmin_kernel<<<dim3(BATCH / 64), dim3(256), 0, stream>>>(
        z_e, emb, e_sq, idx, out + O_IDX);
    scatter_kernel<<<dim3(BATCH / 64), dim3(256), 0, stream>>>(
        z_e, emb, idx, out + O_ZQ, dw, cs, loss);
    finalize_cluster<<<dim3(1), dim3(1024), 0, stream>>>(
        ema_cs, cs, loss, out, n_ws);
    finalize_emb<<<dim3(KC), dim3(256), 0, stream>>>(
        ema_w, dw, out + O_NCS, n_ws, out + O_EMB, out + O_NEW);
}

// Round 2
// 395.991 us; speedup vs baseline: 5.2451x; 5.2451x over previous
//
#include <hip/hip_runtime.h>
#include <hip/hip_bf16.h>
#include <math.h>

#define BATCH 65536
#define DIM 256
#define KC 1024
#define COMMIT 0.25f
#define DECAY 0.99f
#define EPSV 1e-5f

// Output layout (floats, concatenated in reference return order)
#define O_ZQ   0                       // 65536*256
#define O_LOSS 16777216                // 1
#define O_PERP 16777217                // 1
#define O_IDX  16777218                // 65536 (indices written as float values)
#define O_EMB  16842754                // 1024*256 new_embedding
#define O_NCS  17104898                // 1024 new_ema_cluster_size
#define O_NEW  17105922                // 1024*256 new_ema_w

typedef __attribute__((ext_vector_type(8))) short bf16x8;
typedef __attribute__((ext_vector_type(4))) float f32x4;

__device__ __forceinline__ unsigned short bf16_rne(float x) {
    unsigned u = __builtin_bit_cast(unsigned, x);
    unsigned r = (u + 0x7FFFu + ((u >> 16) & 1u)) >> 16;
    return (unsigned short)r;
}
__device__ __forceinline__ float bf16_to_f(unsigned short h) {
    unsigned u = ((unsigned)h) << 16;
    return __builtin_bit_cast(float, u);
}

// ---------------- zero accumulators (ws is re-poisoned 0xAA every launch) ---
__global__ __launch_bounds__(256) void zero_kernel(float* __restrict__ dw,
                                                   float* __restrict__ cs,
                                                   float* __restrict__ loss) {
    int i = blockIdx.x * 256 + threadIdx.x;
    if (i < KC * DIM) dw[i] = 0.0f;
    if (i < KC) cs[i] = 0.0f;
    if (i == 0) loss[0] = 0.0f;
}

// ---------------- emb -> bf16 hi/lo split + e_sq ---------------------------
__global__ __launch_bounds__(64) void prep_kernel(const float* __restrict__ emb,
                                                  unsigned short* __restrict__ ehi,
                                                  unsigned short* __restrict__ elo,
                                                  float* __restrict__ e_sq) {
    int k = blockIdx.x;
    int lane = threadIdx.x;
    const float4* ep = (const float4*)(emb + (size_t)k * DIM);
    float4 e = ep[lane];
    float x[4] = {e.x, e.y, e.z, e.w};
    unsigned h[4], l[4];
    float s = 0.0f;
    #pragma unroll
    for (int j = 0; j < 4; ++j) {
        h[j] = bf16_rne(x[j]);
        l[j] = bf16_rne(x[j] - bf16_to_f((unsigned short)h[j]));
        s += x[j] * x[j];
    }
    uint2 ph = make_uint2(h[0] | (h[1] << 16), h[2] | (h[3] << 16));
    uint2 pl = make_uint2(l[0] | (l[1] << 16), l[2] | (l[3] << 16));
    ((uint2*)(ehi + (size_t)k * DIM))[lane] = ph;
    ((uint2*)(elo + (size_t)k * DIM))[lane] = pl;
    for (int off = 32; off; off >>= 1) s += __shfl_down(s, off, 64);
    if (lane == 0) e_sq[k] = s;
}

// ---------------- MFMA distance + argmin -----------------------------------
// 512 blocks x 256 thr (4 waves). 128 rows/block; wave w owns rows w*32..+31
// (2 m-frags of 16). A (z, bf16 hi/lo) lives in registers for full K=256.
// N=1024 swept in 16 chunks of 64 codes staged in LDS (row stride 528B:
// 132 dw == 4 mod 32 -> 2-way bank aliasing only, which is free).
#define CH_ROWS 64
#define ROW_US 264   /* 264 ushorts = 528 B padded row stride */
__global__ __launch_bounds__(256, 2) void argmin_kernel(
        const float* __restrict__ z_e,
        const unsigned short* __restrict__ ehi,
        const unsigned short* __restrict__ elo,
        const float* __restrict__ e_sq,
        int* __restrict__ idx_out, float* __restrict__ idx_f_out) {
    __shared__ __align__(16) unsigned short bhi_s[CH_ROWS * ROW_US];
    __shared__ __align__(16) unsigned short blo_s[CH_ROWS * ROW_US];
    __shared__ float esq_s[KC];

    int tid = threadIdx.x;
    int w = tid >> 6;
    int lane = tid & 63;
    int m16 = lane & 15;
    int quad = lane >> 4;
    int base_m = blockIdx.x * 128 + w * 32;

    // stage e_sq once
    #pragma unroll
    for (int i = 0; i < 4; ++i) esq_s[tid + i * 256] = e_sq[tid + i * 256];

    // load + split A fragments: A[m=lane&15][k=quad*8+j]
    bf16x8 ahi[2][8], alo[2][8];
    #pragma unroll
    for (int f = 0; f < 2; ++f) {
        const float* zr = z_e + (size_t)(base_m + f * 16 + m16) * DIM;
        #pragma unroll
        for (int ks = 0; ks < 8; ++ks) {
            const float4* p = (const float4*)(zr + ks * 32 + quad * 8);
            float4 x0 = p[0], x1 = p[1];
            float xs[8] = {x0.x, x0.y, x0.z, x0.w, x1.x, x1.y, x1.z, x1.w};
            #pragma unroll
            for (int j = 0; j < 8; ++j) {
                unsigned short h = bf16_rne(xs[j]);
                unsigned short l = bf16_rne(xs[j] - bf16_to_f(h));
                ahi[f][ks][j] = (short)h;
                alo[f][ks][j] = (short)l;
            }
        }
    }

    float best0[4] = {1e30f, 1e30f, 1e30f, 1e30f};
    float best1[4] = {1e30f, 1e30f, 1e30f, 1e30f};
    int bk0[4] = {0, 0, 0, 0};
    int bk1[4] = {0, 0, 0, 0};

    for (int chunk = 0; chunk < 16; ++chunk) {
        __syncthreads();
        // stage 64 codes (hi+lo) into padded LDS
        const int4* gh = (const int4*)(ehi + (size_t)chunk * CH_ROWS * DIM);
        const int4* gl = (const int4*)(elo + (size_t)chunk * CH_ROWS * DIM);
        #pragma unroll
        for (int i = 0; i < 8; ++i) {
            int c = tid + i * 256;       // 16B-unit index, row-major
            int r = c >> 5;
            int col = c & 31;
            int4 vh = gh[c];
            int4 vl = gl[c];
            *(int4*)((char*)bhi_s + r * 528 + col * 16) = vh;
            *(int4*)((char*)blo_s + r * 528 + col * 16) = vl;
        }
        __syncthreads();

        #pragma unroll
        for (int f = 0; f < 4; ++f) {
            f32x4 acc0 = {0.f, 0.f, 0.f, 0.f};
            f32x4 acc1 = {0.f, 0.f, 0.f, 0.f};
            const unsigned short* bh_base = bhi_s + (f * 16 + m16) * ROW_US + quad * 8;
            const unsigned short* bl_base = blo_s + (f * 16 + m16) * ROW_US + quad * 8;
            #pragma unroll
            for (int ks = 0; ks < 8; ++ks) {
                bf16x8 bh = *(const bf16x8*)(bh_base + ks * 32);
                bf16x8 bl = *(const bf16x8*)(bl_base + ks * 32);
                acc0 = __builtin_amdgcn_mfma_f32_16x16x32_bf16(ahi[0][ks], bh, acc0, 0, 0, 0);
                acc1 = __builtin_amdgcn_mfma_f32_16x16x32_bf16(ahi[1][ks], bh, acc1, 0, 0, 0);
                acc0 = __builtin_amdgcn_mfma_f32_16x16x32_bf16(ahi[0][ks], bl, acc0, 0, 0, 0);
                acc1 = __builtin_amdgcn_mfma_f32_16x16x32_bf16(ahi[1][ks], bl, acc1, 0, 0, 0);
                acc0 = __builtin_amdgcn_mfma_f32_16x16x32_bf16(alo[0][ks], bh, acc0, 0, 0, 0);
                acc1 = __builtin_amdgcn_mfma_f32_16x16x32_bf16(alo[1][ks], bh, acc1, 0, 0, 0);
            }
            int col = chunk * 64 + f * 16 + m16;
            float es = esq_s[col];
            #pragma unroll
            for (int r = 0; r < 4; ++r) {
                float d0 = es - 2.0f * acc0[r];
                float d1 = es - 2.0f * acc1[r];
                if (d0 < best0[r]) { best0[r] = d0; bk0[r] = col; }
                if (d1 < best1[r]) { best1[r] = d1; bk1[r] = col; }
            }
        }
    }

    // reduce across the 16 lanes (lane&15) sharing each row; tie -> lower k
    #pragma unroll
    for (int off = 1; off < 16; off <<= 1) {
        #pragma unroll
        for (int r = 0; r < 4; ++r) {
            float ov0 = __shfl_xor(best0[r], off, 64);
            int   ok0 = __shfl_xor(bk0[r], off, 64);
            if (ov0 < best0[r] || (ov0 == best0[r] && ok0 < bk0[r])) { best0[r] = ov0; bk0[r] = ok0; }
            float ov1 = __shfl_xor(best1[r], off, 64);
            int   ok1 = __shfl_xor(bk1[r], off, 64);
            if (ov1 < best1[r] || (ov1 == best1[r] && ok1 < bk1[r])) { best1[r] = ov1; bk1[r] = ok1; }
        }
    }
    if (m16 == 0) {
        #pragma unroll
        for (int r = 0; r < 4; ++r) {
            int row0 = base_m + quad * 4 + r;
            int row1 = base_m + 16 + quad * 4 + r;
            idx_out[row0] = bk0[r];
            idx_f_out[row0] = (float)bk0[r];
            idx_out[row1] = bk1[r];
            idx_f_out[row1] = (float)bk1[r];
        }
    }
}

// ---------------- gather z_q, loss, cluster_size, dw ------------------------
__global__ __launch_bounds__(256) void scatter_kernel(
        const float* __restrict__ z_e, const float* __restrict__ emb,
        const int* __restrict__ idx, float* __restrict__ zq_out,
        float* __restrict__ dw, float* __restrict__ cs,
        float* __restrict__ loss) {
    int tid = threadIdx.x;   // = d
    int row0 = blockIdx.x * 64;
    float lsum = 0.0f;
    for (int r = 0; r < 64; ++r) {
        int row = row0 + r;
        int k = idx[row];
        float z = z_e[(size_t)row * DIM + tid];
        float q = emb[(size_t)k * DIM + tid];
        zq_out[(size_t)row * DIM + tid] = z + (q - z);
        float dlt = q - z;
        lsum += dlt * dlt;
        atomicAdd(&dw[(size_t)k * DIM + tid], z);
        if (tid == 0) atomicAdd(&cs[k], 1.0f);
    }
    __shared__ float red[256];
    red[tid] = lsum;
    __syncthreads();
    for (int s = 128; s; s >>= 1) {
        if (tid < s) red[tid] += red[tid + s];
        __syncthreads();
    }
    if (tid == 0) atomicAdd(loss, red[0]);
}

// ---------------- per-cluster EMA, n, perplexity, loss ----------------------
__global__ __launch_bounds__(1024) void finalize_cluster(
        const float* __restrict__ ema_cs, const float* __restrict__ cs,
        const float* __restrict__ loss, float* __restrict__ out,
        float* __restrict__ n_ws) {
    __shared__ float s1[1024];
    __shared__ float s2[1024];
    int t = threadIdx.x;
    float c = cs[t];
    float ncs = DECAY * ema_cs[t] + (1.0f - DECAY) * c;
    out[O_NCS + t] = ncs;
    float p = c / (float)BATCH;
    s1[t] = ncs;
    s2[t] = p * logf(p + 1e-10f);
    __syncthreads();
    for (int s = 512; s; s >>= 1) {
        if (t < s) { s1[t] += s1[t + s]; s2[t] += s2[t + s]; }
        __syncthreads();
    }
    if (t == 0) {
        n_ws[0] = s1[0];
        out[O_PERP] = expf(-s2[0]);
        out[O_LOSS] = COMMIT * loss[0] / (float)((size_t)BATCH * DIM);
    }
}

// ---------------- new_ema_w and new_embedding -------------------------------
__global__ __launch_bounds__(256) void finalize_emb(
        const float* __restrict__ ema_w, const float* __restrict__ dw,
        const float* __restrict__ ncs_arr, const float* __restrict__ n_ws,
        float* __restrict__ out_emb, float* __restrict__ out_emaw) {
    int k = blockIdx.x;
    int d = threadIdx.x;
    size_t i = (size_t)k * DIM + d;
    float w = DECAY * ema_w[i] + (1.0f - DECAY) * dw[i];
    out_emaw[i] = w;
    float n = n_ws[0];
    float ncs = ncs_arr[k];
    float smoothed = (ncs + EPSV) / (n + (float)KC * EPSV) * n;
    out_emb[i] = w / smoothed;
}

extern "C" void kernel_launch(void* const* d_in, const int* in_sizes, int n_in,
                              void* d_out, int out_size, void* d_ws, size_t ws_size,
                              hipStream_t stream) {
    const float* z_e    = (const float*)d_in[0];
    const float* emb    = (const float*)d_in[1];
    const float* ema_cs = (const float*)d_in[2];
    const float* ema_w  = (const float*)d_in[3];
    float* out = (float*)d_out;
    float* ws = (float*)d_ws;

    // workspace layout
    float* e_sq = ws;                          // 1024
    int*   idx  = (int*)(ws + 1024);           // 65536
    float* cs   = ws + 1024 + 65536;           // 1024
    float* loss = cs + 1024;                   // 1
    float* n_ws = loss + 1;                    // 1
    float* dw   = n_ws + 1;                    // 1024*256
    unsigned short* ehi = (unsigned short*)(dw + KC * DIM);  // 1024*256 bf16
    unsigned short* elo = ehi + KC * DIM;                    // 1024*256 bf16

    zero_kernel<<<dim3(1024), dim3(256), 0, stream>>>(dw, cs, loss);
    prep_kernel<<<dim3(KC), dim3(64), 0, stream>>>(emb, ehi, elo, e_sq);
    argmin_kernel<<<dim3(BATCH / 128), dim3(256), 0, stream>>>(
        z_e, ehi, elo, e_sq, idx, out + O_IDX);
    scatter_kernel<<<dim3(BATCH / 64), dim3(256), 0, stream>>>(
        z_e, emb, idx, out + O_ZQ, dw, cs, loss);
    finalize_cluster<<<dim3(1), dim3(1024), 0, stream>>>(
        ema_cs, cs, loss, out, n_ws);
    finalize_emb<<<dim3(KC), dim3(256), 0, stream>>>(
        ema_w, dw, out + O_NCS, n_ws, out + O_EMB, out + O_NEW);
}